// Round 3
// baseline (2831.928 us; speedup 1.0000x reference)
//
#include <hip/hip_runtime.h>

#define H 65
#define T_STEPS 1024

typedef _Float16 half_t;
typedef _Float16 half2_t __attribute__((ext_vector_type(2)));

// Guaranteed v_dot2_f32_f16: builtin if available, else inline asm.
static __device__ __forceinline__ float dot2(half2_t a, half2_t b, float c) {
#if __has_builtin(__builtin_amdgcn_fdot2)
  return __builtin_amdgcn_fdot2(a, b, c, false);
#else
  float d;
  asm("v_dot2_f32_f16 %0, %1, %2, %3" : "=v"(d) : "v"(a), "v"(b), "v"(c));
  return d;
#endif
}

// Swap with lane^1 (BitMode swizzle: xor=1, and=0x1F)
static __device__ __forceinline__ float swz_xor1(float v) {
  int r = __builtin_amdgcn_ds_swizzle(__builtin_bit_cast(int, v), 0x041F);
  return __builtin_bit_cast(float, r);
}

#define LOG2E 1.44269504089f

static __device__ __forceinline__ float fast_sigm(float v) {
  float e = __builtin_amdgcn_exp2f(-LOG2E * v);
  return __builtin_amdgcn_rcpf(1.f + e);
}
static __device__ __forceinline__ float fast_tanh(float v) {
  float a = __builtin_fabsf(v);
  float e = __builtin_amdgcn_exp2f(-2.f * LOG2E * a);
  float t = (1.f - e) * __builtin_amdgcn_rcpf(1.f + e);
  return v < 0.f ? -t : t;
}

// One block per batch row, 320 threads:
//   tid 0..129   : layer-0 columns. q=tid, column j=q>>1, K-half hf=q&1.
//   tid 130..259 : layer-1 columns, q=tid-130.
//   tid 260..319 : x prefetch (distance-3 pipeline).
// Each column thread owns ALL 4 gates of column j over its K-half (33 of 65
// half2 pairs of the concatenated [x;h] 130-vector). One ds_swizzle xor-1
// butterfly completes the dot; both lanes redundantly run act+cell update.
// h is double-buffered in LDS by step parity -> ONE barrier per step.
// Software pipeline: layer 0 computes t=s while layer 1 computes t=s-1.
__global__ __launch_bounds__(320, 3) void lstm_fused(
    const float* __restrict__ x,
    const float* __restrict__ wih0, const float* __restrict__ whh0,
    const float* __restrict__ bih0, const float* __restrict__ bhh0,
    const float* __restrict__ wih1, const float* __restrict__ whh1,
    const float* __restrict__ bih1, const float* __restrict__ bhh1,
    const float* __restrict__ wlin, const float* __restrict__ blin,
    float* __restrict__ out)
{
  // xh[layer][parity][slots]: 0..64 = input part (x for L0, h0 for L1),
  // 65..129 = recurrent h, 130..135 pad. half2 pair p = slots (2p,2p+1);
  // pair 32 spans (x[64], h[0]) -- weights are built on the same
  // concatenated 130-vector so this is consistent.
  __shared__ __align__(16) half_t xh[2][2][136];
  __shared__ float h1f[H];

  const int tid = threadIdx.x;
  const int b   = blockIdx.x;

  const bool isCol = tid < 260;
  const int  l  = (tid >= 130) ? 1 : 0;
  const int  q  = isCol ? (tid - 130 * l) : 0;
  const int  j  = q >> 1;
  const int  hf = q & 1;

  const bool isLd = (tid >= 260);
  const int  u    = tid - 260;

  // ---- weights: 4 gates x 33 half2 pairs, register-resident ----
  // hf=0: pairs 0..32; hf=1: pairs 32..64 with pair 32's weight zeroed
  // (it is fully accounted by the hf=0 lane).
  half2_t w[4][33];
  float hb[4];  // 0.5*bias: both lanes init acc with it; xor1 sum restores bias
  if (isCol) {
    const float* wi = l ? wih1 : wih0;
    const float* wh = l ? whh1 : whh0;
    const float* bi = l ? bih1 : bih0;
    const float* bh = l ? bhh1 : bhh0;
#pragma unroll
    for (int g = 0; g < 4; ++g) {
      const int row = g * H + j;
      const float* wir = wi + row * H;
      const float* whr = wh + row * H;
      hb[g] = 0.5f * (bi[row] + bh[row]);
#pragma unroll
      for (int s = 0; s < 33; ++s) {
        int p = hf * 32 + s;
        int k0 = 2 * p, k1 = 2 * p + 1;
        float e0 = (k0 < H) ? wir[k0] : whr[k0 - H];
        float e1 = (k1 < H) ? wir[k1] : whr[k1 - H];
        if (hf && s == 0) { e0 = 0.f; e1 = 0.f; }
        half2_t v = {(half_t)e0, (half_t)e1};
        w[g][s] = v;
      }
    }
  } else {
#pragma unroll
    for (int g = 0; g < 4; ++g) {
      hb[g] = 0.f;
#pragma unroll
      for (int s = 0; s < 33; ++s) {
        half2_t z = {(half_t)0.f, (half_t)0.f};
        w[g][s] = z;
      }
    }
  }

  // ---- zero LDS (initial h,c = 0; pads stay zero) ----
  for (int i = tid; i < 2 * 2 * 136; i += 320) ((half_t*)xh)[i] = (half_t)0.f;
  if (tid < H) h1f[tid] = 0.f;

  // ---- x prefetch prologue: x_0 -> LDS buf0; x_1, x_2 -> regs ----
  const float* xrow = x + (size_t)b * (size_t)(T_STEPS * H);
  float nxA = 0.f, nxB = 0.f, nnA = 0.f, nnB = 0.f;
  if (isLd) {
    xh[0][0][u] = (half_t)xrow[u];
    if (u < H - 60) xh[0][0][60 + u] = (half_t)xrow[60 + u];
    nxA = xrow[H + u];
    if (u < H - 60) nxB = xrow[H + 60 + u];
    nnA = xrow[2 * H + u];
    if (u < H - 60) nnB = xrow[2 * H + 60 + u];
  }
  __syncthreads();

  float cst = 0.f;  // cell state, replicated in both lanes of the pair

  for (int s = 0; s <= T_STEPS; ++s) {
    const int p = s & 1;
    const bool act = isCol && (l ? (s >= 1) : (s < T_STEPS));
    if (act) {
      const half_t* xb = &xh[l][p][0];
      const uint4* base = (const uint4*)(xb + 64 * hf);  // 16B-aligned
      float a0 = hb[0], a1 = hb[1], a2 = hb[2], a3 = hb[3];
#pragma unroll
      for (int c = 0; c < 8; ++c) {
        uint4 qv = base[c];
        half2_t x0 = __builtin_bit_cast(half2_t, qv.x);
        half2_t x1 = __builtin_bit_cast(half2_t, qv.y);
        half2_t x2 = __builtin_bit_cast(half2_t, qv.z);
        half2_t x3 = __builtin_bit_cast(half2_t, qv.w);
        a0 = dot2(x0, w[0][4 * c + 0], a0);
        a1 = dot2(x0, w[1][4 * c + 0], a1);
        a2 = dot2(x0, w[2][4 * c + 0], a2);
        a3 = dot2(x0, w[3][4 * c + 0], a3);
        a0 = dot2(x1, w[0][4 * c + 1], a0);
        a1 = dot2(x1, w[1][4 * c + 1], a1);
        a2 = dot2(x1, w[2][4 * c + 1], a2);
        a3 = dot2(x1, w[3][4 * c + 1], a3);
        a0 = dot2(x2, w[0][4 * c + 2], a0);
        a1 = dot2(x2, w[1][4 * c + 2], a1);
        a2 = dot2(x2, w[2][4 * c + 2], a2);
        a3 = dot2(x2, w[3][4 * c + 2], a3);
        a0 = dot2(x3, w[0][4 * c + 3], a0);
        a1 = dot2(x3, w[1][4 * c + 3], a1);
        a2 = dot2(x3, w[2][4 * c + 3], a2);
        a3 = dot2(x3, w[3][4 * c + 3], a3);
      }
      {  // tail pair: slot-pair 32 (hf=0) or 64 (hf=1)
        half2_t xt = *(const half2_t*)(xb + 64 + 64 * hf);
        a0 = dot2(xt, w[0][32], a0);
        a1 = dot2(xt, w[1][32], a1);
        a2 = dot2(xt, w[2][32], a2);
        a3 = dot2(xt, w[3][32], a3);
      }
      // K-combine: add partner lane's partial; both lanes get full sums
      a0 += swz_xor1(a0);
      a1 += swz_xor1(a1);
      a2 += swz_xor1(a2);
      a3 += swz_xor1(a3);
      float iv = fast_sigm(a0), fv = fast_sigm(a1);
      float gv = fast_tanh(a2), ov = fast_sigm(a3);
      cst = fv * cst + iv * gv;
      float h = ov * fast_tanh(cst);
      half_t hh = (half_t)h;
      if (hf == 0) {
        xh[l][p ^ 1][65 + j] = hh;           // recurrent operand, next step
      } else {
        if (l == 0) xh[1][p ^ 1][j] = hh;    // feeds layer 1 next superstep
        else if (s == T_STEPS) h1f[j] = h;   // final h1 (t = T-1)
      }
    }
    if (isLd && (s + 1 < T_STEPS)) {
      half_t* xb = &xh[0][p ^ 1][0];
      xb[u] = (half_t)nxA;
      if (u < H - 60) xb[60 + u] = (half_t)nxB;
      nxA = nnA; nxB = nnB;
      if (s + 3 < T_STEPS) {
        const float* xr = xrow + (size_t)(s + 3) * H;
        nnA = xr[u];
        if (u < H - 60) nnB = xr[60 + u];
      }
    }
    __syncthreads();
  }

  // ---- output projection ----
  if (tid == 0) {
    float acc = blin[0];
    for (int jj = 0; jj < H; ++jj) acc += h1f[jj] * wlin[jj];
    out[b] = acc;
  }
}

extern "C" void kernel_launch(void* const* d_in, const int* in_sizes, int n_in,
                              void* d_out, int out_size, void* d_ws, size_t ws_size,
                              hipStream_t stream) {
  const float* x    = (const float*)d_in[0];
  const float* wih0 = (const float*)d_in[1];
  const float* whh0 = (const float*)d_in[2];
  const float* bih0 = (const float*)d_in[3];
  const float* bhh0 = (const float*)d_in[4];
  const float* wih1 = (const float*)d_in[5];
  const float* whh1 = (const float*)d_in[6];
  const float* bih1 = (const float*)d_in[7];
  const float* bhh1 = (const float*)d_in[8];
  const float* wlin = (const float*)d_in[9];
  const float* blin = (const float*)d_in[10];
  float* out = (float*)d_out;

  lstm_fused<<<512, 320, 0, stream>>>(x, wih0, whh0, bih0, bhh0,
                                      wih1, whh1, bih1, bhh1, wlin, blin, out);
}

// Round 4
// 1909.298 us; speedup vs baseline: 1.4832x; 1.4832x over previous
//
#include <hip/hip_runtime.h>

#define H 65
#define T_STEPS 1024
#define NCOL 520          // 2 layers * 260 gate-columns ... /2 cols per thread * 2 khalves
#define NLD  56           // x loader threads
#define BLK  576          // 9 waves

typedef _Float16 half_t;
typedef _Float16 half2_t __attribute__((ext_vector_type(2)));

// Guaranteed v_dot2_f32_f16
static __device__ __forceinline__ float dot2(half2_t a, half2_t b, float c) {
#if __has_builtin(__builtin_amdgcn_fdot2)
  return __builtin_amdgcn_fdot2(a, b, c, false);
#else
  float d;
  asm("v_dot2_f32_f16 %0, %1, %2, %3" : "=v"(d) : "v"(a), "v"(b), "v"(c));
  return d;
#endif
}

// Quad-lane permute via DPP (VALU pipe, no LDS). CTRL: quad_perm encoding.
// 0xB1 = [1,0,3,2] (xor1: swap gate-pair partner), 0x4E = [2,3,0,1] (xor2: K-half partner)
template <int CTRL>
static __device__ __forceinline__ float qperm(float v) {
  int r = __builtin_amdgcn_update_dpp(0, __builtin_bit_cast(int, v), CTRL, 0xF, 0xF, true);
  return __builtin_bit_cast(float, r);
}

#define LOG2E 1.44269504089f
static __device__ __forceinline__ float fast_sigm(float v) {
  float e = __builtin_amdgcn_exp2f(-LOG2E * v);
  return __builtin_amdgcn_rcpf(1.f + e);
}

// One block per batch row, 576 threads, ONE barrier per step.
//   tid 0..519: column threads. l = tid>=260; q = tid - 260*l;
//       j = q>>2 (hidden idx), kh = (q>>1)&1 (K half), g0 = q&1 (gate pair).
//       Thread computes gates {g0, g0+2} of hidden j over K-half kh.
//       Quad 4j..4j+3 combines via DPP: xor2 completes K, xor1 swaps gates.
//       All 4 lanes redundantly run the cell update (c replicated).
//   tid 520..575: x prefetch, distance-3 pipeline.
// h double-buffered in LDS by step parity. L0 computes t=s, L1 t=s-1.
__global__ __launch_bounds__(BLK, 5) void lstm_fused(
    const float* __restrict__ x,
    const float* __restrict__ wih0, const float* __restrict__ whh0,
    const float* __restrict__ bih0, const float* __restrict__ bhh0,
    const float* __restrict__ wih1, const float* __restrict__ whh1,
    const float* __restrict__ bih1, const float* __restrict__ bhh1,
    const float* __restrict__ wlin, const float* __restrict__ blin,
    float* __restrict__ out)
{
  // xh[layer][parity][144]: slots 0..64 = input part (x for L0, h0 for L1),
  // 65..71 zero pad, 72..136 = recurrent h, 137..143 zero pad.
  // K-half kh reads 144B at offset kh*144B (16B aligned). No pair straddles x/h.
  __shared__ __align__(16) half_t xh[2][2][144];
  __shared__ float h1f[H];

  const int tid = threadIdx.x;
  const int b   = blockIdx.x;

  const bool isCol = tid < NCOL;
  const int  l  = (tid >= 260) ? 1 : 0;
  const int  q  = isCol ? (tid - 260 * l) : 0;
  const int  j  = q >> 2;
  const int  kh = (q >> 1) & 1;
  const int  g0 = q & 1;
  const bool gz = (g0 == 0);

  const bool isLd = (tid >= NCOL);
  const int  ld   = tid - NCOL;

  // activation shape constants: gate g0+2 is tanh when g0==0 (gate 2 = g~), else sigm (gate 3 = o)
  const float mreg = gz ? 2.f : 1.f;
  const float msub = mreg - 1.f;

  // ---- register-resident weights: 2 gate-columns x 33 half2 pairs (66 VGPRs) ----
  half2_t w[2][33];
  float hb[2];  // 0.5*bias (both K-half lanes add it; xor2 sum restores full bias)
  if (isCol) {
    const float* wi = l ? wih1 : wih0;
    const float* wh = l ? whh1 : whh0;
    const float* bi = l ? bih1 : bih0;
    const float* bh = l ? bhh1 : bhh0;
#pragma unroll
    for (int cc = 0; cc < 2; ++cc) {
      const int row = (g0 + 2 * cc) * H + j;
      hb[cc] = 0.5f * (bi[row] + bh[row]);
      const float* src = (kh ? wh : wi) + row * H;
#pragma unroll
      for (int pp = 0; pp < 33; ++pp) {
        float e0 = src[2 * pp];
        float e1 = (2 * pp + 1 < H) ? src[2 * pp + 1] : 0.f;
        half2_t v = {(half_t)e0, (half_t)e1};
        w[cc][pp] = v;
      }
    }
  } else {
    hb[0] = hb[1] = 0.f;
#pragma unroll
    for (int cc = 0; cc < 2; ++cc)
#pragma unroll
      for (int pp = 0; pp < 33; ++pp) {
        half2_t z = {(half_t)0.f, (half_t)0.f};
        w[cc][pp] = z;
      }
  }

  // ---- zero LDS (576 halfs == blockDim; initial h,c = 0, pads stay 0) ----
  ((half_t*)xh)[tid] = (half_t)0.f;
  __syncthreads();

  // ---- prologue: x_0 -> LDS[par 0]; x_1, x_2 -> regs ----
  const float* xrow = x + (size_t)b * (size_t)(T_STEPS * H);
  float nxA = 0.f, nxB = 0.f, nnA = 0.f, nnB = 0.f;
  if (isLd) {
    xh[0][0][ld] = (half_t)xrow[ld];
    if (ld < 9) xh[0][0][NLD + ld] = (half_t)xrow[NLD + ld];
    nxA = xrow[H + ld];
    if (ld < 9) nxB = xrow[H + NLD + ld];
    nnA = xrow[2 * H + ld];
    if (ld < 9) nnB = xrow[2 * H + NLD + ld];
  }
  __syncthreads();

  float cst = 0.f;  // cell state, replicated across the 4 quad lanes

  for (int s = 0; s <= T_STEPS; ++s) {
    const int p = s & 1;

    // issue distance-3 global prefetch early (latency overlaps compute)
    float fA = 0.f, fB = 0.f;
    if (isLd && (s + 3 < T_STEPS)) {
      const float* xr = xrow + (size_t)(s + 3) * H;
      fA = xr[ld];
      if (ld < 9) fB = xr[NLD + ld];
    }

    const bool act = isCol && (l ? (s >= 1) : (s < T_STEPS));
    if (act) {
      const half_t* xb = &xh[l][p][0] + 72 * kh;
      float a0 = hb[0], a1 = hb[1];
#pragma unroll
      for (int c = 0; c < 8; ++c) {
        uint4 qv = ((const uint4*)xb)[c];
        half2_t x0 = __builtin_bit_cast(half2_t, qv.x);
        half2_t x1 = __builtin_bit_cast(half2_t, qv.y);
        half2_t x2 = __builtin_bit_cast(half2_t, qv.z);
        half2_t x3 = __builtin_bit_cast(half2_t, qv.w);
        a0 = dot2(x0, w[0][4 * c + 0], a0);
        a1 = dot2(x0, w[1][4 * c + 0], a1);
        a0 = dot2(x1, w[0][4 * c + 1], a0);
        a1 = dot2(x1, w[1][4 * c + 1], a1);
        a0 = dot2(x2, w[0][4 * c + 2], a0);
        a1 = dot2(x2, w[1][4 * c + 2], a1);
        a0 = dot2(x3, w[0][4 * c + 3], a0);
        a1 = dot2(x3, w[1][4 * c + 3], a1);
      }
      {  // tail pair 32: (x[64],0) or (h[64],0)
        half2_t xt = *(const half2_t*)(xb + 64);
        a0 = dot2(xt, w[0][32], a0);
        a1 = dot2(xt, w[1][32], a1);
      }
      // K-combine with kh partner (DPP xor2): full preacts incl. bias
      a0 += qperm<0x4E>(a0);
      a1 += qperm<0x4E>(a1);
      // activations, branchless: a0 -> gate g0 (i/f, sigmoid);
      // a1 -> gate g0+2 (g~: tanh = 2*sigm(2x)-1 when g0==0, else o: sigm)
      float e0 = fast_sigm(a0);
      float e1 = mreg * fast_sigm(mreg * a1) - msub;
      // gate-pair exchange (DPP xor1): even lane has (i,g~), odd has (f,o)
      float p0 = qperm<0xB1>(e0);
      float p1 = qperm<0xB1>(e1);
      float iv = gz ? e0 : p0;
      float fv = gz ? p0 : e0;
      float gv = gz ? e1 : p1;
      float ov = gz ? p1 : e1;
      cst = fv * cst + iv * gv;
      float th = 2.f * fast_sigm(2.f * cst) - 1.f;  // tanh(c)
      float hv = ov * th;
      if ((q & 3) == 0) {
        half_t hh = (half_t)hv;
        if (l == 0) {
          xh[0][p ^ 1][72 + j] = hh;  // own recurrence, next step
          xh[1][p ^ 1][j]      = hh;  // layer-1 input, next superstep
        } else {
          xh[1][p ^ 1][72 + j] = hh;
          if (s == T_STEPS) h1f[j] = hv;  // final h1 (t = T-1)
        }
      }
    }

    // stage x_{s+1} into next-parity buffer; shift prefetch pipeline
    if (isLd && (s + 1 < T_STEPS)) {
      half_t* dst = &xh[0][p ^ 1][0];
      dst[ld] = (half_t)nxA;
      if (ld < 9) dst[NLD + ld] = (half_t)nxB;
      nxA = nnA; nxB = nnB;
      nnA = fA;  nnB = fB;
    }
    __syncthreads();
  }

  // ---- output projection: out[b] = b_lin + h1_final . w_lin ----
  if (tid == 0) {
    float acc = blin[0];
    for (int jj = 0; jj < H; ++jj) acc += h1f[jj] * wlin[jj];
    out[b] = acc;
  }
}

extern "C" void kernel_launch(void* const* d_in, const int* in_sizes, int n_in,
                              void* d_out, int out_size, void* d_ws, size_t ws_size,
                              hipStream_t stream) {
  const float* x    = (const float*)d_in[0];
  const float* wih0 = (const float*)d_in[1];
  const float* whh0 = (const float*)d_in[2];
  const float* bih0 = (const float*)d_in[3];
  const float* bhh0 = (const float*)d_in[4];
  const float* wih1 = (const float*)d_in[5];
  const float* whh1 = (const float*)d_in[6];
  const float* bih1 = (const float*)d_in[7];
  const float* bhh1 = (const float*)d_in[8];
  const float* wlin = (const float*)d_in[9];
  const float* blin = (const float*)d_in[10];
  float* out = (float*)d_out;

  lstm_fused<<<512, BLK, 0, stream>>>(x, wih0, whh0, bih0, bhh0,
                                      wih1, whh1, bih1, bhh1, wlin, blin, out);
}

// Round 5
// 1359.686 us; speedup vs baseline: 2.0828x; 1.4042x over previous
//
#include <hip/hip_runtime.h>

#define H 65
#define T_STEPS 1024

typedef _Float16 half_t;
typedef _Float16 half2_t __attribute__((ext_vector_type(2)));

// Guaranteed v_dot2_f32_f16
static __device__ __forceinline__ float dot2(half2_t a, half2_t b, float c) {
#if __has_builtin(__builtin_amdgcn_fdot2)
  return __builtin_amdgcn_fdot2(a, b, c, false);
#else
  float d;
  asm("v_dot2_f32_f16 %0, %1, %2, %3" : "=v"(d) : "v"(a), "v"(b), "v"(c));
  return d;
#endif
}

// Quad-lane permute via DPP. 0xB1=[1,0,3,2] (xor1), 0x4E=[2,3,0,1] (xor2)
template <int CTRL>
static __device__ __forceinline__ float qperm(float v) {
  int r = __builtin_amdgcn_update_dpp(0, __builtin_bit_cast(int, v), CTRL, 0xF, 0xF, true);
  return __builtin_bit_cast(float, r);
}

// ds_swizzle BitMode: offset = (xor<<10)|(or<<5)|and(0x1F)
template <int PAT>
static __device__ __forceinline__ float swz(float v) {
  int r = __builtin_amdgcn_ds_swizzle(__builtin_bit_cast(int, v), PAT);
  return __builtin_bit_cast(float, r);
}

#define LOG2E 1.44269504089f
static __device__ __forceinline__ float fast_sigm(float v) {
  float e = __builtin_amdgcn_exp2f(-LOG2E * v);
  return __builtin_amdgcn_rcpf(1.f + e);
}

// select [a,b,c,d][idx], branchless
static __device__ __forceinline__ float pick(int idx, float a, float b, float c, float d) {
  float lo = (idx & 1) ? b : a;
  float hi = (idx & 1) ? d : c;
  return (idx & 2) ? hi : lo;
}

// One block per batch row, 512 threads = 8 waves, 2 blocks/CU, ONE barrier/step.
// Quad scheme: quad = tid>>2 in [0,128) -> unit (l,j): quads 0..64 = (0, j),
// quads 65..127 = (1, j=0..62). Lane roles in quad: kh=(tid>>1)&1 K-half,
// g0=tid&1 gate pair. DPP xor2 completes K, xor1 exchanges gate pairs.
// Missing units (l=1, j=63,64) = 8 gate-columns: K-distributed across wave 7
// (9 extra weight pairs/lane, swizzle-reduce + swizzle-gather, in-wave update).
// x staging rides on wave 6. h double-buffered in LDS by parity.
// Pipeline: L0 computes t=s, L1 computes t=s-1.
__global__ __launch_bounds__(512, 4) void lstm_fused(
    const float* __restrict__ x,
    const float* __restrict__ wih0, const float* __restrict__ whh0,
    const float* __restrict__ bih0, const float* __restrict__ bhh0,
    const float* __restrict__ wih1, const float* __restrict__ whh1,
    const float* __restrict__ bih1, const float* __restrict__ bhh1,
    const float* __restrict__ wlin, const float* __restrict__ blin,
    float* __restrict__ out)
{
  // xh[layer][parity][144]: 0..64 input part (x for L0, h0 for L1),
  // 65..71 zero pad, 72..136 recurrent h, 137..143 zero pad.
  __shared__ __align__(16) half_t xh[2][2][144];
  __shared__ float h1f[H];

  const int tid = threadIdx.x;
  const int b   = blockIdx.x;

  const int quad = tid >> 2;
  const int l  = (quad >= 65) ? 1 : 0;
  const int j  = quad - 65 * l;
  const int kh = (tid >> 1) & 1;
  const int g0 = tid & 1;
  const bool gz = (g0 == 0);
  const float mreg = gz ? 2.f : 1.f;  // gate g0+2 is tanh (g~) iff g0==0
  const float msub = mreg - 1.f;

  // ---- regular weights: 2 gate-columns x K-half = 66 half2 VGPRs ----
  half2_t w[2][33];
  float hb[2];  // 0.5*bias; xor2 K-combine restores full bias
  {
    const float* wi = l ? wih1 : wih0;
    const float* wh = l ? whh1 : whh0;
    const float* bi = l ? bih1 : bih0;
    const float* bh = l ? bhh1 : bhh0;
#pragma unroll
    for (int cc = 0; cc < 2; ++cc) {
      const int row = (g0 + 2 * cc) * H + j;
      hb[cc] = 0.5f * (bi[row] + bh[row]);
      const float* src = (kh ? wh : wi) + row * H;
#pragma unroll
      for (int pp = 0; pp < 33; ++pp) {
        float e0 = src[2 * pp];
        float e1 = (2 * pp + 1 < H) ? src[2 * pp + 1] : 0.f;
        half2_t v = {(half_t)e0, (half_t)e1};
        w[cc][pp] = v;
      }
    }
  }

  // ---- EC: extra columns (l=1, j=63/64), spread over wave 7 ----
  // w7 = tid-448; ec = w7>>3 in [0,8) -> column (gate=ec&3, j=63+(ec>>2));
  // ck = w7&7 chunk; side = ck>>2 (0=x-side,1=h-side); sck = ck&3.
  // Lane covers side pair-indices es = 9*sck + i (valid es<33; rest zeroed,
  // operand reads land in the zero pads -> contribute 0).
  const bool isW7 = (tid >= 448);
  const int  w7   = tid - 448;
  const int  ec   = w7 >> 3;
  const int  ck   = w7 & 7;
  const int  side = ck >> 2;
  const int  sck  = ck & 3;
  const int  ecoff = side * 144 + 36 * sck;  // byte offset within xh[1][p]
  half2_t ecw[9];
  float ecbias = 0.f;
  float cec = 0.f;
  if (isW7) {
    const int gec = ec & 3;
    const int jec = 63 + (ec >> 2);
    const int row = gec * H + jec;
    const float* src = (side ? whh1 : wih1) + row * H;
#pragma unroll
    for (int i = 0; i < 9; ++i) {
      int es = 9 * sck + i;
      float e0 = (es < 33) ? src[2 * es] : 0.f;
      float e1 = (es < 33 && 2 * es + 1 < H) ? src[2 * es + 1] : 0.f;
      half2_t v = {(half_t)e0, (half_t)e1};
      ecw[i] = v;
    }
    if (ck == 0) ecbias = bih1[row] + bhh1[row];
  } else {
#pragma unroll
    for (int i = 0; i < 9; ++i) {
      half2_t z = {(half_t)0.f, (half_t)0.f};
      ecw[i] = z;
    }
  }

  // ---- loaders: wave 6 stages x (distance-3 pipeline) ----
  const bool isW6 = (tid >= 384) && (tid < 448);
  const int  u    = tid - 384;

  // ---- zero LDS (initial h,c=0; pads stay 0 forever) ----
  for (int i = tid; i < 2 * 2 * 144; i += 512) ((half_t*)xh)[i] = (half_t)0.f;
  __syncthreads();

  const float* xrow = x + (size_t)b * (size_t)(T_STEPS * H);
  float nxA = 0.f, nxB = 0.f, nnA = 0.f, nnB = 0.f;
  if (isW6) {
    xh[0][0][u] = (half_t)xrow[u];
    if (u == 0) xh[0][0][64] = (half_t)xrow[64];
    nxA = xrow[H + u];
    if (u == 0) nxB = xrow[H + 64];
    nnA = xrow[2 * H + u];
    if (u == 0) nnB = xrow[2 * H + 64];
  }
  __syncthreads();

  float cst = 0.f;  // cell state (replicated across quad lanes)

  for (int s = 0; s <= T_STEPS; ++s) {
    const int p = s & 1;

    // distance-3 global prefetch (latency hidden across the step)
    float fA = 0.f, fB = 0.f;
    if (isW6 && (s + 3 < T_STEPS)) {
      const float* xr = xrow + (size_t)(s + 3) * H;
      fA = xr[u];
      if (u == 0) fB = xr[64];
    }

    const bool act = l ? (s >= 1) : (s < T_STEPS);
    if (act) {
      const half_t* xb = &xh[l][p][0] + 72 * kh;
      float a0 = hb[0], a1 = hb[1];
#pragma unroll
      for (int c = 0; c < 8; ++c) {
        uint4 qv = ((const uint4*)xb)[c];
        half2_t x0 = __builtin_bit_cast(half2_t, qv.x);
        half2_t x1 = __builtin_bit_cast(half2_t, qv.y);
        half2_t x2 = __builtin_bit_cast(half2_t, qv.z);
        half2_t x3 = __builtin_bit_cast(half2_t, qv.w);
        a0 = dot2(x0, w[0][4 * c + 0], a0);
        a1 = dot2(x0, w[1][4 * c + 0], a1);
        a0 = dot2(x1, w[0][4 * c + 1], a0);
        a1 = dot2(x1, w[1][4 * c + 1], a1);
        a0 = dot2(x2, w[0][4 * c + 2], a0);
        a1 = dot2(x2, w[1][4 * c + 2], a1);
        a0 = dot2(x3, w[0][4 * c + 3], a0);
        a1 = dot2(x3, w[1][4 * c + 3], a1);
      }
      {
        half2_t xt = *(const half2_t*)(xb + 64);  // tail pair (elem 64 + pad)
        a0 = dot2(xt, w[0][32], a0);
        a1 = dot2(xt, w[1][32], a1);
      }
      a0 += qperm<0x4E>(a0);  // K-combine with kh partner
      a1 += qperm<0x4E>(a1);
      float e0 = fast_sigm(a0);
      float e1 = mreg * fast_sigm(mreg * a1) - msub;  // tanh via 2σ(2x)-1
      float p0 = qperm<0xB1>(e0);  // gate-pair exchange
      float p1 = qperm<0xB1>(e1);
      float iv = gz ? e0 : p0;
      float fv = gz ? p0 : e0;
      float gv = gz ? e1 : p1;
      float ov = gz ? p1 : e1;
      cst = fv * cst + iv * gv;
      float th = 2.f * fast_sigm(2.f * cst) - 1.f;
      float hv = ov * th;
      if ((tid & 3) == 0) {
        half_t hh = (half_t)hv;
        if (l == 0) {
          xh[0][p ^ 1][72 + j] = hh;  // own recurrence
          xh[1][p ^ 1][j]      = hh;  // layer-1 input
        } else {
          xh[1][p ^ 1][72 + j] = hh;
          if (s == T_STEPS) h1f[j] = hv;
        }
      }
    }

    // ---- EC path (wave 7 only): columns (l=1, j=63,64) ----
    if (isW7 && s >= 1) {
      const char* xb1 = (const char*)&xh[1][p][0];
      float aec = ecbias;
#pragma unroll
      for (int i = 0; i < 9; ++i) {
        unsigned qv = *(const unsigned*)(xb1 + ecoff + 4 * i);
        aec = dot2(__builtin_bit_cast(half2_t, qv), ecw[i], aec);
      }
      aec += swz<0x041F>(aec);  // xor1
      aec += swz<0x081F>(aec);  // xor2
      aec += swz<0x101F>(aec);  // xor4: full column preact in all 8 lanes
      const int gec = ec & 3;
      float me = (gec == 2) ? 2.f : 1.f;
      float A  = me * fast_sigm(me * aec) - (me - 1.f);
      float Bv = swz<0x201F>(A);   // act of ec^1
      float Cv = swz<0x401F>(A);   // act of ec^2
      float Dv = swz<0x401F>(Bv);  // act of ec^3
      float iv2 = pick(gec ^ 0, A, Bv, Cv, Dv);
      float fv2 = pick(gec ^ 1, A, Bv, Cv, Dv);
      float gv2 = pick(gec ^ 2, A, Bv, Cv, Dv);
      float ov2 = pick(gec ^ 3, A, Bv, Cv, Dv);
      cec = fv2 * cec + iv2 * gv2;
      float hec = ov2 * (2.f * fast_sigm(2.f * cec) - 1.f);
      if (ck == 0 && (ec & 3) == 0) {  // w7==0 -> j63, w7==32 -> j64
        const int jec = 63 + (ec >> 2);
        xh[1][p ^ 1][72 + jec] = (half_t)hec;
        if (s == T_STEPS) h1f[jec] = hec;
      }
    }

    // stage x_{s+1}; shift prefetch pipeline
    if (isW6 && (s + 1 < T_STEPS)) {
      half_t* dst = &xh[0][p ^ 1][0];
      dst[u] = (half_t)nxA;
      if (u == 0) dst[64] = (half_t)nxB;
      nxA = nnA; nxB = nnB;
      nnA = fA;  nnB = fB;
    }
    __syncthreads();
  }

  // ---- output projection: out[b] = b_lin + h1_final . w_lin ----
  if (tid == 0) {
    float acc = blin[0];
    for (int jj = 0; jj < H; ++jj) acc += h1f[jj] * wlin[jj];
    out[b] = acc;
  }
}

extern "C" void kernel_launch(void* const* d_in, const int* in_sizes, int n_in,
                              void* d_out, int out_size, void* d_ws, size_t ws_size,
                              hipStream_t stream) {
  const float* x    = (const float*)d_in[0];
  const float* wih0 = (const float*)d_in[1];
  const float* whh0 = (const float*)d_in[2];
  const float* bih0 = (const float*)d_in[3];
  const float* bhh0 = (const float*)d_in[4];
  const float* wih1 = (const float*)d_in[5];
  const float* whh1 = (const float*)d_in[6];
  const float* bih1 = (const float*)d_in[7];
  const float* bhh1 = (const float*)d_in[8];
  const float* wlin = (const float*)d_in[9];
  const float* blin = (const float*)d_in[10];
  float* out = (float*)d_out;

  lstm_fused<<<512, 512, 0, stream>>>(x, wih0, whh0, bih0, bhh0,
                                      wih1, whh1, bih1, bhh1, wlin, blin, out);
}